// Round 1
// baseline (663.707 us; speedup 1.0000x reference)
//
#include <hip/hip_runtime.h>

#define NB 128
#define NM 1024
#define NK 32
#define CUT2 25.0f

// One thread per center atom. Block = 256 threads = 256 consecutive centers
// (quarter of a molecule). Molecule's 1024 atoms staged in LDS as
// float4{x,y,z,|p|^2}. Selection: fully-unrolled 32-deep register insertion
// sort keyed on d2 (strict <, scan order ascending j => stable ties by index,
// matching jax.lax.top_k).
__global__ __launch_bounds__(256) void radius_knn(const float* __restrict__ pos,
                                                  float* __restrict__ out)
{
#pragma clang fp contract(off)
  __shared__ float4 atoms[NM];
  const int tid  = threadIdx.x;
  const int c    = blockIdx.x * 256 + tid;   // global center index
  const int mol  = c >> 10;
  const int mloc = c & (NM - 1);

  // stage molecule into LDS (x, y, z, sq) — sq with the reference's op order
  const float* mp = pos + (size_t)mol * NM * 3;
  for (int j = tid; j < NM; j += 256) {
    float x = mp[3*j+0], y = mp[3*j+1], z = mp[3*j+2];
    float sq = (x*x + y*y) + z*z;
    atoms[j] = make_float4(x, y, z, sq);
  }
  __syncthreads();

  const float4 me = atoms[mloc];

  float bd[NK];
  int   bi[NK];
#pragma unroll
  for (int i = 0; i < NK; ++i) { bd[i] = __builtin_inff(); bi[i] = mloc; }

  for (int j = 0; j < NM; ++j) {
    float4 a = atoms[j];            // uniform LDS address -> broadcast
    // reference: d2 = max(sq_m + sq_n - 2*dot, 0), dot = (xx+yy)+zz, no FMA
    float dot = (me.x*a.x + me.y*a.y) + me.z*a.z;
    float t   = me.w + a.w;
    float d2  = t - 2.0f * dot;
    d2 = fmaxf(d2, 0.0f);
    if (d2 <= CUT2 && d2 < bd[NK-1]) {
#pragma unroll
      for (int i = NK-1; i >= 1; --i) {
        bool  ci  = d2 < bd[i];
        bool  cim = d2 < bd[i-1];
        float nv  = cim ? bd[i-1] : d2;
        int   ni  = cim ? bi[i-1] : j;
        bd[i] = ci ? nv : bd[i];
        bi[i] = ci ? ni : bi[i];
      }
      bool c0 = d2 < bd[0];
      bd[0] = c0 ? d2 : bd[0];
      bi[0] = c0 ? j  : bi[0];
    }
  }

  // ---- emit edges: [src | dst | weight | vec] planes, all float32 ----
  const long long E = (long long)NB * NM * NK;
  float* o_src = out;
  float* o_dst = out + E;
  float* o_w   = out + 2*E;
  float* o_v   = out + 3*E;

  float4* ps = (float4*)(o_src + (size_t)c * NK);
  float4* pd = (float4*)(o_dst + (size_t)c * NK);
  float4* pw = (float4*)(o_w   + (size_t)c * NK);
  float4* pv = (float4*)(o_v   + (size_t)c * NK * 3);

  const float  fc   = (float)c;
  const float4 dstv = make_float4(fc, fc, fc, fc);
  const float  base = (float)(mol * NM);

#pragma unroll
  for (int q = 0; q < 8; ++q) {
    float sv[4], wv[4], vv[12];
#pragma unroll
    for (int u = 0; u < 4; ++u) {
      int   k     = 4*q + u;
      int   idx   = bi[k];                 // padded slots hold mloc
      bool  valid = (bd[k] <= CUT2);
      float4 a = atoms[idx];
      // reference: edge_vec = pos[neighbor] - pos[center] (direct subtraction)
      float vx = a.x - me.x;
      float vy = a.y - me.y;
      float vz = a.z - me.z;
      bool  selfp = (idx == mloc);
      bool  wm    = valid && !selfp;
      float d2s   = (vx*vx + vy*vy) + vz*vz;   // reference d2sel op order
      wv[u] = wm ? sqrtf(d2s) : 0.0f;
      sv[u] = base + (float)idx;
      vv[3*u+0] = vx; vv[3*u+1] = vy; vv[3*u+2] = vz;
    }
    ps[q] = make_float4(sv[0], sv[1], sv[2], sv[3]);
    pd[q] = dstv;
    pw[q] = make_float4(wv[0], wv[1], wv[2], wv[3]);
    pv[3*q+0] = make_float4(vv[0], vv[1],  vv[2],  vv[3]);
    pv[3*q+1] = make_float4(vv[4], vv[5],  vv[6],  vv[7]);
    pv[3*q+2] = make_float4(vv[8], vv[9],  vv[10], vv[11]);
  }
}

extern "C" void kernel_launch(void* const* d_in, const int* in_sizes, int n_in,
                              void* d_out, int out_size, void* d_ws, size_t ws_size,
                              hipStream_t stream) {
  const float* pos = (const float*)d_in[0];
  float* out = (float*)d_out;
  dim3 grid((NB * NM) / 256);
  dim3 block(256);
  hipLaunchKernelGGL(radius_knn, grid, block, 0, stream, pos, out);
}

// Round 2
// 239.882 us; speedup vs baseline: 2.7668x; 2.7668x over previous
//
#include <hip/hip_runtime.h>

#define NB 128
#define NM 1024
#define NK 32
#define CUT2 25.0f
#define NSLOT 96   // per-thread candidate list slots (mean ~30, 96 = >10 sigma)

// Prepass: pack pos -> {x,y,z,|p|^2} so the scan phase can stream candidates
// with uniform (scalar) loads. sq op order matches reference: (x*x+y*y)+z*z.
__global__ __launch_bounds__(256) void pack_atoms(const float* __restrict__ pos,
                                                  float4* __restrict__ packed)
{
#pragma clang fp contract(off)
  int i = blockIdx.x * 256 + threadIdx.x;
  float x = pos[3*i+0], y = pos[3*i+1], z = pos[3*i+2];
  packed[i] = make_float4(x, y, z, (x*x + y*y) + z*z);
}

// One thread per center. Phase 1: scan 1024 candidates, append within-cutoff
// indices to a per-thread LDS list (slot-major layout -> conflict-free).
// Phase 2: insertion-sort only the ~30-50 survivors into 32 register slots.
// d2 key recomputed bit-identically to phase 1 (expanded form, contract off),
// so ordering/ties exactly match jax.lax.top_k(-d2) with stable tie-by-index.
template <bool PACKED>
__global__ __launch_bounds__(256, 2) void radius_knn(const float* __restrict__ pos,
                                                     const float4* __restrict__ packed,
                                                     float* __restrict__ out)
{
#pragma clang fp contract(off)
  __shared__ float4 atoms[NM];                      // 16 KB
  __shared__ unsigned short lists[NSLOT * 256];     // 48 KB, [slot][thread]

  const int tid  = threadIdx.x;
  const int c    = blockIdx.x * 256 + tid;
  const int mol  = c >> 10;
  const int mloc = c & (NM - 1);

  // stage molecule into LDS
  if (PACKED) {
    const float4* mp = packed + (size_t)mol * NM;
    for (int j = tid; j < NM; j += 256) atoms[j] = mp[j];
  } else {
    const float* mp = pos + (size_t)mol * NM * 3;
    for (int j = tid; j < NM; j += 256) {
      float x = mp[3*j+0], y = mp[3*j+1], z = mp[3*j+2];
      atoms[j] = make_float4(x, y, z, (x*x + y*y) + z*z);
    }
  }
  __syncthreads();

  const float4 me = atoms[mloc];

  // ---- phase 1: scan + compact ----
  int cnt = 0;
  if (PACKED) {
    const float4* mp = packed + (size_t)mol * NM;   // uniform addr -> s_load
#pragma unroll 4
    for (int j = 0; j < NM; ++j) {
      float4 a  = mp[j];
      float dot = (me.x*a.x + me.y*a.y) + me.z*a.z;
      float d2  = (me.w + a.w) - 2.0f * dot;
      d2 = fmaxf(d2, 0.0f);
      int slot = cnt < NSLOT ? cnt : (NSLOT - 1);
      lists[slot * 256 + tid] = (unsigned short)j;  // unconditional, branch-free
      cnt += (d2 <= CUT2) ? 1 : 0;
    }
  } else {
#pragma unroll 4
    for (int j = 0; j < NM; ++j) {
      float4 a  = atoms[j];
      float dot = (me.x*a.x + me.y*a.y) + me.z*a.z;
      float d2  = (me.w + a.w) - 2.0f * dot;
      d2 = fmaxf(d2, 0.0f);
      int slot = cnt < NSLOT ? cnt : (NSLOT - 1);
      lists[slot * 256 + tid] = (unsigned short)j;
      cnt += (d2 <= CUT2) ? 1 : 0;
    }
  }
  if (cnt > NSLOT) cnt = NSLOT;   // safety clamp (astronomically rare)

  // ---- phase 2: sort survivors into 32 register slots ----
  float bd[NK];
  int   bi[NK];
#pragma unroll
  for (int i = 0; i < NK; ++i) { bd[i] = __builtin_inff(); bi[i] = mloc; }

  for (int k = 0; k < cnt; ++k) {
    int j = lists[k * 256 + tid];
    float4 a  = atoms[j];
    float dot = (me.x*a.x + me.y*a.y) + me.z*a.z;   // bit-identical to phase 1
    float d2  = (me.w + a.w) - 2.0f * dot;
    d2 = fmaxf(d2, 0.0f);
    if (d2 < bd[NK-1]) {
#pragma unroll
      for (int i = NK-1; i >= 1; --i) {
        bool  ci  = d2 < bd[i];
        bool  cim = d2 < bd[i-1];
        float nv  = cim ? bd[i-1] : d2;
        int   ni  = cim ? bi[i-1] : j;
        bd[i] = ci ? nv : bd[i];
        bi[i] = ci ? ni : bi[i];
      }
      bool c0 = d2 < bd[0];
      bd[0] = c0 ? d2 : bd[0];
      bi[0] = c0 ? j  : bi[0];
    }
  }

  // ---- emit edges: [src | dst | weight | vec] planes, all float32 ----
  const long long E = (long long)NB * NM * NK;
  float* o_src = out;
  float* o_dst = out + E;
  float* o_w   = out + 2*E;
  float* o_v   = out + 3*E;

  float4* ps = (float4*)(o_src + (size_t)c * NK);
  float4* pd = (float4*)(o_dst + (size_t)c * NK);
  float4* pw = (float4*)(o_w   + (size_t)c * NK);
  float4* pv = (float4*)(o_v   + (size_t)c * NK * 3);

  const float  fc   = (float)c;
  const float4 dstv = make_float4(fc, fc, fc, fc);
  const float  base = (float)(mol * NM);

#pragma unroll
  for (int q = 0; q < 8; ++q) {
    float sv[4], wv[4], vv[12];
#pragma unroll
    for (int u = 0; u < 4; ++u) {
      int   k     = 4*q + u;
      int   idx   = bi[k];                 // padded slots hold mloc
      bool  valid = (bd[k] <= CUT2);
      float4 a = atoms[idx];
      float vx = a.x - me.x;
      float vy = a.y - me.y;
      float vz = a.z - me.z;
      bool  selfp = (idx == mloc);
      bool  wm    = valid && !selfp;
      float d2s   = (vx*vx + vy*vy) + vz*vz;   // reference d2sel op order
      wv[u] = wm ? sqrtf(d2s) : 0.0f;
      sv[u] = base + (float)idx;
      vv[3*u+0] = vx; vv[3*u+1] = vy; vv[3*u+2] = vz;
    }
    ps[q] = make_float4(sv[0], sv[1], sv[2], sv[3]);
    pd[q] = dstv;
    pw[q] = make_float4(wv[0], wv[1], wv[2], wv[3]);
    pv[3*q+0] = make_float4(vv[0], vv[1],  vv[2],  vv[3]);
    pv[3*q+1] = make_float4(vv[4], vv[5],  vv[6],  vv[7]);
    pv[3*q+2] = make_float4(vv[8], vv[9],  vv[10], vv[11]);
  }
}

extern "C" void kernel_launch(void* const* d_in, const int* in_sizes, int n_in,
                              void* d_out, int out_size, void* d_ws, size_t ws_size,
                              hipStream_t stream) {
  const float* pos = (const float*)d_in[0];
  float* out = (float*)d_out;
  const size_t need = (size_t)NB * NM * sizeof(float4);   // 2 MB packed atoms

  dim3 grid((NB * NM) / 256);
  dim3 block(256);
  if (ws_size >= need) {
    float4* packed = (float4*)d_ws;
    hipLaunchKernelGGL(pack_atoms, grid, block, 0, stream, pos, packed);
    hipLaunchKernelGGL((radius_knn<true>), grid, block, 0, stream, pos, packed, out);
  } else {
    hipLaunchKernelGGL((radius_knn<false>), grid, block, 0, stream, pos, (const float4*)nullptr, out);
  }
}